// Round 4
// baseline (573.441 us; speedup 1.0000x reference)
//
#include <hip/hip_runtime.h>

// Problem constants (fixed by setup_inputs)
constexpr int BB = 16;         // batch
constexpr int SS = 4096;       // seq
constexpr int DD = 1024;       // hidden dim
constexpr int KK = 65536;      // num keys
constexpr int GM = BB * SS;    // GEMM M = 65536
constexpr int GK = DD;         // GEMM K = 1024

typedef __attribute__((ext_vector_type(8))) short bf16x8;
typedef __attribute__((ext_vector_type(4))) float f32x4;
typedef __attribute__((ext_vector_type(8))) unsigned short ushort8;

#define GLD_LDS16(g, l)                                                        \
  __builtin_amdgcn_global_load_lds(                                            \
      (const __attribute__((address_space(1))) void*)(g),                      \
      (__attribute__((address_space(3))) void*)(l), 16, 0, 0)

__device__ __forceinline__ unsigned short f2bf(float x) {
  unsigned u = __float_as_uint(x);
  u += 0x7fffu + ((u >> 16) & 1u);   // RNE
  return (unsigned short)(u >> 16);
}

// ---------------- fp32 -> bf16 conversion (W only now) ----------------------
__global__ void cvt_bf16(const float* __restrict__ in,
                         unsigned short* __restrict__ out, int n8) {
  int stride = gridDim.x * blockDim.x;
  for (int i = blockIdx.x * blockDim.x + threadIdx.x; i < n8; i += stride) {
    const float4* p = (const float4*)in + (size_t)i * 2;
    float4 a = p[0], b = p[1];
    ushort8 r;
    r[0] = f2bf(a.x); r[1] = f2bf(a.y); r[2] = f2bf(a.z); r[3] = f2bf(a.w);
    r[4] = f2bf(b.x); r[5] = f2bf(b.y); r[6] = f2bf(b.z); r[7] = f2bf(b.w);
    *(ushort8*)(out + (size_t)i * 8) = r;
  }
}

// ---------------- q transpose: csig[16][1024] -> qT[1024][16] ---------------
__global__ __launch_bounds__(256) void qt_prep(const float* __restrict__ csig,
                                               float* __restrict__ qT) {
  int e = blockIdx.x * 256 + threadIdx.x;   // 64 blocks cover 16384
  int b = e >> 10, d = e & 1023;
  qT[d * 16 + b] = csig[e];
}

// =====================  GEMM: 256x256 tile, 8-phase, fused A-cvt ============
// C[m,n] = sum_k A[m,k]*W[n,k] + bias[n], A read as FP32 and converted to
// bf16 during reg-staging (saves the 512 MB cvt round-trip).  BM=BN=256,
// BK=64, 8 waves (2Mx4N), LDS 128 KiB (2buf x (A32K + B32K), bf16).
// A path: global fp32 loads (ALD, issued 2 phases early) -> cvt -> ds_write
// (AWR, at the slot where gload_lds used to be; buffer-free ledger identical
// to R3).  B path: global_load_lds (bf16 W).  vmcnt(12) at ph4/ph8 = the 12
// vmem ops of the last 2 phase-regions -> forces next tile's B landed.
// ds_write visibility: writer's own lgkmcnt(0) next phase + >=2 barriers
// before first read.  K-tail: tile pointers clamped to 15 (garbage loads are
// ledger-safe: they overwrite only already-consumed quarters, never read).

#define LDA8(AH, BUF) do {                                                     \
  _Pragma("unroll") for (int ms = 0; ms < 4; ++ms) {                           \
    int rowa = (wm << 7) + ((AH) << 6) + (ms << 4) + fr;                       \
    _Pragma("unroll") for (int ks = 0; ks < 2; ++ks) {                         \
      int ia = ((rowa << 6) + (ks << 5) + (kg << 3)) ^ sw;                     \
      ar[ms * 2 + ks] = *(const bf16x8*)&lds[(BUF) + ia]; } }                  \
} while (0)

#define LDB4(NP, BUF) do {                                                     \
  _Pragma("unroll") for (int nn = 0; nn < 2; ++nn) {                           \
    int rowb = (wn << 6) + ((((NP) << 1) + nn) << 4) + fr;                     \
    _Pragma("unroll") for (int ks = 0; ks < 2; ++ks) {                         \
      int ib = ((rowb << 6) + (ks << 5) + (kg << 3)) ^ sw;                     \
      br[(((NP) << 1) + nn) * 2 + ks] = *(const bf16x8*)&lds[(BUF) + ib]; } }  \
} while (0)

#define MFMAQ(AH, NP) do {                                                     \
  _Pragma("unroll") for (int ms = 0; ms < 4; ++ms)                             \
  _Pragma("unroll") for (int nn = 0; nn < 2; ++nn)                             \
  _Pragma("unroll") for (int ks = 0; ks < 2; ++ks)                             \
    acc[((AH) << 2) + ms][((NP) << 1) + nn] =                                  \
      __builtin_amdgcn_mfma_f32_16x16x32_bf16(ar[ms * 2 + ks],                 \
        br[(((NP) << 1) + nn) * 2 + ks],                                       \
        acc[((AH) << 2) + ms][((NP) << 1) + nn], 0, 0, 0);                     \
} while (0)

// B staging: global_load_lds of bf16 W quarter QJ into LDS base LB
#define STAGEQ(GB, LB, QJ)                                                     \
  GLD_LDS16((GB) + (size_t)(((QJ) << 6) + srq) * GK + ssc,                     \
            &lds[(LB) + ((((QJ) << 9) + (wv << 6)) << 3)])

// A staging: load 2 quarters (8 fp32 each) of tile TP into reg pair R[4]
#define ALD(R, TP, QA, QB) do {                                                \
  const float* pa_ = (TP) + (size_t)(((QA) << 6) + srq) * GK + ssc;            \
  const float* pb_ = (TP) + (size_t)(((QB) << 6) + srq) * GK + ssc;            \
  R[0] = *(const float4*)pa_; R[1] = *(const float4*)(pa_ + 4);                \
  R[2] = *(const float4*)pb_; R[3] = *(const float4*)(pb_ + 4);                \
} while (0)

// A staging: cvt regs -> bf16, ds_write_b128 into quarters QA,QB at base LB
#define AWR(LB, QA, QB, R) do {                                                \
  ushort8 w0_, w1_;                                                            \
  w0_[0] = f2bf(R[0].x); w0_[1] = f2bf(R[0].y); w0_[2] = f2bf(R[0].z);         \
  w0_[3] = f2bf(R[0].w); w0_[4] = f2bf(R[1].x); w0_[5] = f2bf(R[1].y);         \
  w0_[6] = f2bf(R[1].z); w0_[7] = f2bf(R[1].w);                                \
  w1_[0] = f2bf(R[2].x); w1_[1] = f2bf(R[2].y); w1_[2] = f2bf(R[2].z);         \
  w1_[3] = f2bf(R[2].w); w1_[4] = f2bf(R[3].x); w1_[5] = f2bf(R[3].y);         \
  w1_[6] = f2bf(R[3].z); w1_[7] = f2bf(R[3].w);                                \
  *(ushort8*)&lds[(LB) + ((((QA) << 9) + (wv << 6)) << 3) + (lane << 3)] = w0_;\
  *(ushort8*)&lds[(LB) + ((((QB) << 9) + (wv << 6)) << 3) + (lane << 3)] = w1_;\
} while (0)

#define PH_MID do { __builtin_amdgcn_s_barrier();                              \
  asm volatile("s_waitcnt lgkmcnt(0)" ::: "memory");                           \
  __builtin_amdgcn_sched_barrier(0);                                           \
  __builtin_amdgcn_s_setprio(1); } while (0)

#define PH_END do { __builtin_amdgcn_s_setprio(0);                             \
  __builtin_amdgcn_sched_barrier(0);                                           \
  __builtin_amdgcn_s_barrier(); } while (0)

#define PH_END_V(N) do { __builtin_amdgcn_s_setprio(0);                        \
  asm volatile("s_waitcnt vmcnt(" #N ")" ::: "memory");                        \
  __builtin_amdgcn_sched_barrier(0);                                           \
  __builtin_amdgcn_s_barrier(); } while (0)

__global__ __launch_bounds__(512, 2) void gemm8(
    const float* __restrict__ A,            // GM x GK fp32 (hidden)
    const unsigned short* __restrict__ Bm,  // DD x GK bf16 (W row-major)
    const float* __restrict__ bias,         // DD fp32
    float* __restrict__ out) {
  __shared__ unsigned short lds[65536];     // 128 KiB

  // bijective XCD swizzle: 1024 wgs, 8 XCDs -> 128 contiguous per XCD
  int g = blockIdx.x;
  int t = ((g & 7) << 7) + (g >> 3);
  int mt = t >> 2, nt = t & 3;              // 256 M-tiles x 4 N-tiles
  int m0 = mt << 8, n0 = nt << 8;

  int tid = threadIdx.x, lane = tid & 63, wv = tid >> 6;
  int wm = wv >> 2, wn = wv & 3;            // 2M x 4N waves, each owns 128x64
  int fr = lane & 15, kg = lane >> 4;
  int sw = (fr & 7) << 3;                   // read-side swizzle (elem idx)

  int srq = (wv << 3) + (lane >> 3);        // staging row within quarter
  int ssc = (((lane & 7) ^ ((lane >> 3) & 7)) << 3);  // pre-swizzled src col

  const float* Ag = A + (size_t)m0 * GK;
  const unsigned short* Bg = Bm + (size_t)n0 * GK;

  f32x4 acc[8][4] = {};
  bf16x8 ar[8], br[8];
  float4 sAX[4], sAY[4];

  // ---- prologue: buf0 <- tile0 full; buf1 <- tile1{Aq02,B}; preload regs ----
  {
    const float* a1 = Ag + 64;
    const float* a2 = Ag + 128;
    STAGEQ(Bg, 16384, 0); STAGEQ(Bg, 16384, 1);
    STAGEQ(Bg, 16384, 2); STAGEQ(Bg, 16384, 3);
    STAGEQ(Bg + 64, 49152, 0); STAGEQ(Bg + 64, 49152, 1);
    STAGEQ(Bg + 64, 49152, 2); STAGEQ(Bg + 64, 49152, 3);
    ALD(sAX, Ag, 0, 2); ALD(sAY, Ag, 1, 3);
    AWR(0, 0, 2, sAX);  AWR(0, 1, 3, sAY);
    ALD(sAX, a1, 0, 2);
    AWR(32768, 0, 2, sAX);
    ALD(sAX, a1, 1, 3);   // -> iter0 ph1 writes O{13}
    ALD(sAY, a2, 0, 2);   // -> iter0 ph2 writes E'{02}
    __syncthreads();      // drains vmcnt+lgkmcnt: buf0 full, buf1{A02,B} in
  }

  for (int i = 0; i < 8; ++i) {
    int e2 = 2 * i + 2 > 15 ? 15 : 2 * i + 2;
    int o2 = 2 * i + 3 > 15 ? 15 : 2 * i + 3;
    int e4 = 2 * i + 4 > 15 ? 15 : 2 * i + 4;
    const float* aE2 = Ag + (size_t)e2 * 64;
    const float* aO2 = Ag + (size_t)o2 * 64;
    const float* aE4 = Ag + (size_t)e4 * 64;
    const unsigned short* bE2 = Bg + (size_t)e2 * 64;
    const unsigned short* bO2 = Bg + (size_t)o2 * 64;
    // ph1: Q0 of tile 2i (buf0); write O{Aq1,Aq3} (loaded prev ph7)
    LDA8(0, 0); LDB4(0, 16384);
    AWR(32768, 1, 3, sAX);
    PH_MID; MFMAQ(0, 0); PH_END;
    // ph2: Q1; write E'{Aq0,Aq2} (loaded prev ph8)
    LDB4(1, 16384);
    AWR(0, 0, 2, sAY);
    PH_MID; MFMAQ(0, 1); PH_END;
    // ph3: Q2; load E'{Aq1,Aq3}; B-stage E' q01
    LDA8(1, 0);
    ALD(sAX, aE2, 1, 3);
    STAGEQ(bE2, 16384, 0); STAGEQ(bE2, 16384, 1);
    PH_MID; MFMAQ(1, 0); PH_END;
    // ph4: Q3; load O'{Aq0,Aq2}; B-stage E' q23; vmcnt(12)
    ALD(sAY, aO2, 0, 2);
    STAGEQ(bE2, 16384, 2); STAGEQ(bE2, 16384, 3);
    PH_MID; MFMAQ(1, 1); PH_END_V(12);
    // ph5: Q0 of tile 2i+1 (buf1); write E'{Aq1,Aq3}
    LDA8(0, 32768); LDB4(0, 49152);
    AWR(0, 1, 3, sAX);
    PH_MID; MFMAQ(0, 0); PH_END;
    // ph6: Q1; write O'{Aq0,Aq2}
    LDB4(1, 49152);
    AWR(32768, 0, 2, sAY);
    PH_MID; MFMAQ(0, 1); PH_END;
    // ph7: Q2; load O'{Aq1,Aq3}; B-stage O' q01
    LDA8(1, 32768);
    ALD(sAX, aO2, 1, 3);
    STAGEQ(bO2, 49152, 0); STAGEQ(bO2, 49152, 1);
    PH_MID; MFMAQ(1, 0); PH_END;
    // ph8: Q3; load E''{Aq0,Aq2}; B-stage O' q23; vmcnt(12)
    ALD(sAY, aE4, 0, 2);
    STAGEQ(bO2, 49152, 2); STAGEQ(bO2, 49152, 3);
    PH_MID; MFMAQ(1, 1); PH_END_V(12);
  }

  // ---- epilogue: C/D layout col=lane&15, row=(lane>>4)*4+j ----
  int r0 = kg << 2, cc = fr;
#pragma unroll
  for (int ni = 0; ni < 4; ++ni) {
    int gcol = n0 + (wn << 6) + (ni << 4) + cc;
    float bv = bias[gcol];
#pragma unroll
    for (int mi = 0; mi < 8; ++mi) {
      int gr = m0 + (wm << 7) + (mi << 4) + r0;
#pragma unroll
      for (int j = 0; j < 4; ++j) {
        int grow = gr + j;                       // m index = b*4096 + s
        size_t o = ((size_t)(grow + (grow >> 12)) << 10) + gcol;
        out[o] = acc[mi][ni][j] + bv;
      }
    }
  }
}

// ---------------- cos partial dots: thread-per-key, d-split x4 --------------
__global__ __launch_bounds__(256) void cos_part4(
    const float* __restrict__ keys,    // KK x DD
    const float* __restrict__ qT,      // DD x 16
    float* __restrict__ pd,            // [4][KK][16]
    float* __restrict__ pn) {          // [4][KK]
  __shared__ float kt[32][256];        // 32 KB
  __shared__ float qs[256 * 16];       // 16 KB

  int tid = threadIdx.x;
  int kgrp = blockIdx.x & 255, dc = blockIdx.x >> 8;
  int k0 = kgrp << 8, d0 = dc << 8;

  {
    const float4* src = (const float4*)(qT + (size_t)d0 * 16);
    float4* dst = (float4*)qs;
#pragma unroll
    for (int i = 0; i < 4; ++i) dst[tid + i * 256] = src[tid + i * 256];
  }

  float acc[16] = {0.f, 0.f, 0.f, 0.f, 0.f, 0.f, 0.f, 0.f,
                   0.f, 0.f, 0.f, 0.f, 0.f, 0.f, 0.f, 0.f};
  float nrm = 0.f;

  int srow = tid >> 3, scol = (tid & 7) << 2;
  const float* gsrc = keys + (size_t)(k0 + srow) * DD + d0 + scol;

  float4 stg[8];
#pragma unroll
  for (int i = 0; i < 8; ++i)
    stg[i] = *(const float4*)(gsrc + (size_t)i * 32 * DD);

  for (int t = 0; t < 8; ++t) {
#pragma unroll
    for (int i = 0; i < 8; ++i) {
      int r = (i << 5) + srow;
#pragma unroll
      for (int j = 0; j < 4; ++j) {
        int dd = scol + j;
        kt[dd][r ^ (((dd >> 2) & 7) << 2)] = stg[i][j];
      }
    }
    __syncthreads();

    if (t + 1 < 8) {
#pragma unroll
      for (int i = 0; i < 8; ++i)
        stg[i] = *(const float4*)(gsrc + (size_t)i * 32 * DD + (t + 1) * 32);
    }

    const float* qb = qs + (t << 5) * 16;
#pragma unroll
    for (int dd = 0; dd < 32; ++dd) {
      float kv = kt[dd][tid ^ (((dd >> 2) & 7) << 2)];
      float4 q0 = *(const float4*)(qb + dd * 16 + 0);
      float4 q1 = *(const float4*)(qb + dd * 16 + 4);
      float4 q2 = *(const float4*)(qb + dd * 16 + 8);
      float4 q3 = *(const float4*)(qb + dd * 16 + 12);
      acc[0]  = fmaf(kv, q0.x, acc[0]);  acc[1]  = fmaf(kv, q0.y, acc[1]);
      acc[2]  = fmaf(kv, q0.z, acc[2]);  acc[3]  = fmaf(kv, q0.w, acc[3]);
      acc[4]  = fmaf(kv, q1.x, acc[4]);  acc[5]  = fmaf(kv, q1.y, acc[5]);
      acc[6]  = fmaf(kv, q1.z, acc[6]);  acc[7]  = fmaf(kv, q1.w, acc[7]);
      acc[8]  = fmaf(kv, q2.x, acc[8]);  acc[9]  = fmaf(kv, q2.y, acc[9]);
      acc[10] = fmaf(kv, q2.z, acc[10]); acc[11] = fmaf(kv, q2.w, acc[11]);
      acc[12] = fmaf(kv, q3.x, acc[12]); acc[13] = fmaf(kv, q3.y, acc[13]);
      acc[14] = fmaf(kv, q3.z, acc[14]); acc[15] = fmaf(kv, q3.w, acc[15]);
      nrm = fmaf(kv, kv, nrm);
    }
    __syncthreads();
  }

  int k = k0 + tid;
  float4* po = (float4*)(pd + ((size_t)dc * KK + k) * 16);
  po[0] = make_float4(acc[0], acc[1], acc[2], acc[3]);
  po[1] = make_float4(acc[4], acc[5], acc[6], acc[7]);
  po[2] = make_float4(acc[8], acc[9], acc[10], acc[11]);
  po[3] = make_float4(acc[12], acc[13], acc[14], acc[15]);
  pn[(size_t)dc * KK + k] = nrm;
}

// ---------------- combine partials -> cos -> per-block argmax ---------------
__global__ __launch_bounds__(256) void cos_combine(
    const float* __restrict__ pd, const float* __restrict__ pn,
    float* __restrict__ pscore, int* __restrict__ pidx) {
  __shared__ float rs[4][16];
  __shared__ int ri[4][16];
  int tid = threadIdx.x, lane = tid & 63, w = tid >> 6;
  int k = blockIdx.x * 256 + tid;

  float d[16] = {0.f, 0.f, 0.f, 0.f, 0.f, 0.f, 0.f, 0.f,
                 0.f, 0.f, 0.f, 0.f, 0.f, 0.f, 0.f, 0.f};
  float nrm = 0.f;
#pragma unroll
  for (int dc = 0; dc < 4; ++dc) {
    const float4* p = (const float4*)(pd + ((size_t)dc * KK + k) * 16);
#pragma unroll
    for (int i = 0; i < 4; ++i) {
      float4 v = p[i];
      d[i * 4 + 0] += v.x; d[i * 4 + 1] += v.y;
      d[i * 4 + 2] += v.z; d[i * 4 + 3] += v.w;
    }
    nrm += pn[(size_t)dc * KK + k];
  }
  float inv = rsqrtf(fmaxf(nrm, 1e-24f));

#pragma unroll
  for (int b = 0; b < 16; ++b) {
    float s = d[b] * inv;
    int i = k;
#pragma unroll
    for (int off = 32; off; off >>= 1) {
      float s2 = __shfl_xor(s, off);
      int i2 = __shfl_xor(i, off);
      if (s2 > s || (s2 == s && i2 < i)) { s = s2; i = i2; }
    }
    if (lane == 0) { rs[w][b] = s; ri[w][b] = i; }
  }
  __syncthreads();
  if (tid < 16) {
    float bs = rs[0][tid]; int bi = ri[0][tid];
#pragma unroll
    for (int w2 = 1; w2 < 4; ++w2) {
      float s = rs[w2][tid]; int i = ri[w2][tid];
      if (s > bs || (s == bs && i < bi)) { bs = s; bi = i; }
    }
    pscore[(size_t)tid * gridDim.x + blockIdx.x] = bs;
    pidx[(size_t)tid * gridDim.x + blockIdx.x] = bi;
  }
}

// ---------------- final argmax reduce + token gather + l2norm ---------------
__global__ __launch_bounds__(256) void select_write(
    const float* __restrict__ pscore, const int* __restrict__ pidx, int nb,
    const int* __restrict__ ktv, const float* __restrict__ values,
    float* __restrict__ out) {
  __shared__ float ss[4];
  __shared__ int si[4];
  __shared__ float snrm;
  __shared__ int swin;
  int b = blockIdx.x, tid = threadIdx.x, lane = tid & 63, wv = tid >> 6;

  float best = -1e30f;
  int bidx = 0x7fffffff;
  for (int t = tid; t < nb; t += 256) {
    float s = pscore[(size_t)b * nb + t];
    int i = pidx[(size_t)b * nb + t];
    if (s > best || (s == best && i < bidx)) { best = s; bidx = i; }
  }
#pragma unroll
  for (int off = 32; off; off >>= 1) {
    float s = __shfl_xor(best, off);
    int i = __shfl_xor(bidx, off);
    if (s > best || (s == best && i < bidx)) { best = s; bidx = i; }
  }
  if (lane == 0) { ss[wv] = best; si[wv] = bidx; }
  __syncthreads();
  if (tid == 0) {
    float bs = ss[0]; int bi = si[0];
    for (int w2 = 1; w2 < 4; ++w2)
      if (ss[w2] > bs || (ss[w2] == bs && si[w2] < bi)) { bs = ss[w2]; bi = si[w2]; }
    swin = ktv[bi];   // key_to_value mapping
  }
  __syncthreads();
  int idx = swin;

  float4 v = ((const float4*)(values + (size_t)idx * DD))[tid];
  float nrm = v.x * v.x + v.y * v.y + v.z * v.z + v.w * v.w;
#pragma unroll
  for (int off = 32; off; off >>= 1) nrm += __shfl_xor(nrm, off);
  if (lane == 0) ss[wv] = nrm;
  __syncthreads();
  if (tid == 0) snrm = rsqrtf(fmaxf(ss[0] + ss[1] + ss[2] + ss[3], 1e-24f));
  __syncthreads();
  float inv = snrm;

  float4 o;
  o.x = v.x * inv; o.y = v.y * inv; o.z = v.z * inv; o.w = v.w * inv;
  ((float4*)(out + (((size_t)b * (SS + 1) + SS) << 10)))[tid] = o;
}

// ---------------- launcher ---------------------------------------------------
extern "C" void kernel_launch(void* const* d_in, const int* in_sizes, int n_in,
                              void* d_out, int out_size, void* d_ws,
                              size_t ws_size, hipStream_t stream) {
  const float* hidden = (const float*)d_in[0];
  const float* csig   = (const float*)d_in[1];
  const float* keys   = (const float*)d_in[2];
  const float* values = (const float*)d_in[3];
  const int*   ktv    = (const int*)d_in[4];
  const float* W      = (const float*)d_in[5];
  const float* bias   = (const float*)d_in[6];
  float* out = (float*)d_out;

  char* ws = (char*)d_ws;
  size_t off = 0;
  unsigned short* wbf = (unsigned short*)(ws + off); off += (size_t)DD * GK * 2;
  float* pd     = (float*)(ws + off); off += (size_t)4 * KK * 16 * 4;
  float* pn     = (float*)(ws + off); off += (size_t)4 * KK * 4;
  float* pscore = (float*)(ws + off); off += (size_t)16 * 256 * 4;
  int*   pidx   = (int*)(ws + off);   off += (size_t)16 * 256 * 4;
  float* qT     = (float*)(ws + off); off += (size_t)DD * 16 * 4;

  // 1) W conversion + q transpose (tiny)
  cvt_bf16<<<512, 256, 0, stream>>>(W, wbf, DD * GK / 8);
  qt_prep<<<64, 256, 0, stream>>>(csig, qT);

  // 2) cos-similarity: partial dots (d-split x4) + combine/argmax
  cos_part4<<<1024, 256, 0, stream>>>(keys, qT, pd, pn);
  cos_combine<<<256, 256, 0, stream>>>(pd, pn, pscore, pidx);

  // 3) GEMM + bias into out rows s<4096 (256^2 8-phase, fused fp32->bf16 A)
  gemm8<<<1024, 512, 0, stream>>>(hidden, wbf, bias, out);

  // 4) final reduce + token row s=4096
  select_write<<<BB, 256, 0, stream>>>(pscore, pidx, 256, ktv, values, out);
}

// Round 6
// 412.089 us; speedup vs baseline: 1.3915x; 1.3915x over previous
//
#include <hip/hip_runtime.h>

// Problem constants (fixed by setup_inputs)
constexpr int BB = 16;         // batch
constexpr int SS = 4096;       // seq
constexpr int DD = 1024;       // hidden dim
constexpr int KK = 65536;      // num keys
constexpr int GM = BB * SS;    // GEMM M = 65536
constexpr int GK = DD;         // GEMM K = 1024

typedef __attribute__((ext_vector_type(8))) short bf16x8;
typedef __attribute__((ext_vector_type(4))) float f32x4;
typedef __attribute__((ext_vector_type(8))) unsigned short ushort8;

#define GLD_LDS16(g, l)                                                        \
  __builtin_amdgcn_global_load_lds(                                            \
      (const __attribute__((address_space(1))) void*)(g),                      \
      (__attribute__((address_space(3))) void*)(l), 16, 0, 0)

__device__ __forceinline__ unsigned short f2bf(float x) {
  unsigned u = __float_as_uint(x);
  u += 0x7fffu + ((u >> 16) & 1u);   // RNE
  return (unsigned short)(u >> 16);
}

// ---------------- cvt body: one float8 per thread ---------------------------
__device__ __forceinline__ void cvt_body(const float* __restrict__ in,
                                         unsigned short* __restrict__ out,
                                         int i) {
  const float4* p = (const float4*)in + (size_t)i * 2;
  float4 a = p[0], b = p[1];
  ushort8 r;
  r[0] = f2bf(a.x); r[1] = f2bf(a.y); r[2] = f2bf(a.z); r[3] = f2bf(a.w);
  r[4] = f2bf(b.x); r[5] = f2bf(b.y); r[6] = f2bf(b.z); r[7] = f2bf(b.w);
  *(ushort8*)(out + (size_t)i * 8) = r;
}

// ---------------- cos body: thread-per-key, d-split x4, scalar-q ------------
// Block (kgrp, dc): keys [kgrp*256,+256), d [dc*256,+256).  Keys staged
// transposed [dd][key] in LDS with XOR swizzle (conflict-free both sides).
// q read DIRECTLY from csig with wave-uniform addresses -> SMEM/L1 pipe,
// zero LDS-pipe pressure (R3's 4x ds_read_b128/dd was the bottleneck).
__device__ __forceinline__ void cos_body(const float* __restrict__ keys,
                                         const float* __restrict__ csig,
                                         float* __restrict__ pd,
                                         float* __restrict__ pn,
                                         float (*kt)[256], int bid, int tid) {
  int kgrp = bid & 255, dc = bid >> 8;
  int k0 = kgrp << 8, d0 = dc << 8;

  float acc[16] = {0.f, 0.f, 0.f, 0.f, 0.f, 0.f, 0.f, 0.f,
                   0.f, 0.f, 0.f, 0.f, 0.f, 0.f, 0.f, 0.f};
  float nrm = 0.f;

  int srow = tid >> 3, scol = (tid & 7) << 2;
  const float* gsrc = keys + (size_t)(k0 + srow) * DD + d0 + scol;

  float4 stg[8];
#pragma unroll
  for (int i = 0; i < 8; ++i)
    stg[i] = *(const float4*)(gsrc + (size_t)i * 32 * DD);

  for (int t = 0; t < 8; ++t) {
#pragma unroll
    for (int i = 0; i < 8; ++i) {
      int r = (i << 5) + srow;
#pragma unroll
      for (int j = 0; j < 4; ++j) {
        int dd = scol + j;
        kt[dd][r ^ (((dd >> 2) & 7) << 2)] = stg[i][j];
      }
    }
    __syncthreads();

    if (t + 1 < 8) {   // issue next tile early (T14)
#pragma unroll
      for (int i = 0; i < 8; ++i)
        stg[i] = *(const float4*)(gsrc + (size_t)i * 32 * DD + (t + 1) * 32);
    }

    const float* qb = csig + d0 + (t << 5);   // wave-uniform base
#pragma unroll
    for (int dd = 0; dd < 32; ++dd) {
      float kv = kt[dd][tid ^ (((dd >> 2) & 7) << 2)];
#pragma unroll
      for (int b = 0; b < 16; ++b)
        acc[b] = fmaf(kv, qb[(size_t)b * DD + dd], acc[b]);  // s_load (uniform)
      nrm = fmaf(kv, kv, nrm);
    }
    __syncthreads();
  }

  int k = k0 + tid;
  float4* po = (float4*)(pd + ((size_t)dc * KK + k) * 16);
  po[0] = make_float4(acc[0], acc[1], acc[2], acc[3]);
  po[1] = make_float4(acc[4], acc[5], acc[6], acc[7]);
  po[2] = make_float4(acc[8], acc[9], acc[10], acc[11]);
  po[3] = make_float4(acc[12], acc[13], acc[14], acc[15]);
  pn[(size_t)dc * KK + k] = nrm;
}

// ---------------- fused prep: cos (1024) | cvt hidden (4096x8) | cvt W (512) -
__global__ __launch_bounds__(256) void prep_fused(
    const float* __restrict__ keys, const float* __restrict__ csig,
    float* __restrict__ pd, float* __restrict__ pn,
    const float* __restrict__ hidden, unsigned short* __restrict__ hbf,
    const float* __restrict__ W, unsigned short* __restrict__ wbf) {
  __shared__ float kt[32][256];
  int bid = blockIdx.x, tid = threadIdx.x;
  if (bid < 1024) {
    cos_body(keys, csig, pd, pn, kt, bid, tid);
  } else if (bid < 5120) {
    // hidden: GM*GK/8 = 8388608 chunks; 4096 blocks x 256 thr x 8 chunks
    int base = (bid - 1024) * 256 + tid;
#pragma unroll
    for (int r = 0; r < 8; ++r)
      cvt_body(hidden, hbf, base + r * (4096 * 256));
  } else {
    // W: DD*GK/8 = 131072 chunks; 512 blocks x 256 thr x 1 chunk
    cvt_body(W, wbf, (bid - 5120) * 256 + tid);
  }
}

// ---------------- standalone fallback kernels (serial ws layout) ------------
__global__ __launch_bounds__(256) void cos_part4_k(
    const float* __restrict__ keys, const float* __restrict__ csig,
    float* __restrict__ pd, float* __restrict__ pn) {
  __shared__ float kt[32][256];
  cos_body(keys, csig, pd, pn, kt, blockIdx.x, threadIdx.x);
}

__global__ void cvt_bf16(const float* __restrict__ in,
                         unsigned short* __restrict__ out, int n8) {
  int stride = gridDim.x * blockDim.x;
  for (int i = blockIdx.x * blockDim.x + threadIdx.x; i < n8; i += stride)
    cvt_body(in, out, i);
}

// =====================  GEMM: 256x256 tile, 8-phase (R3-proven) =============
// C[m,n] = sum_k A[m,k]*W[n,k] + bias[n].  BM=BN=256, BK=64, 8 waves (2Mx4N),
// LDS 128 KiB (2 buf x (A 32KB + B 32KB)).  K = 1024 -> 16 K-tiles, 8 iters.
// vmcnt(6) at ph4/ph8 forces next tile fully landed before its first read.
// LDS swizzle: short_idx ^= (row&7)<<3, applied as inverse-permuted GLOBAL
// source + swizzled ds_read (both-sides rule).

#define LDA8(AH, BUF) do {                                                     \
  _Pragma("unroll") for (int ms = 0; ms < 4; ++ms) {                           \
    int rowa = (wm << 7) + ((AH) << 6) + (ms << 4) + fr;                       \
    _Pragma("unroll") for (int ks = 0; ks < 2; ++ks) {                         \
      int ia = ((rowa << 6) + (ks << 5) + (kg << 3)) ^ sw;                     \
      ar[ms * 2 + ks] = *(const bf16x8*)&lds[(BUF) + ia]; } }                  \
} while (0)

#define LDB4(NP, BUF) do {                                                     \
  _Pragma("unroll") for (int nn = 0; nn < 2; ++nn) {                           \
    int rowb = (wn << 6) + ((((NP) << 1) + nn) << 4) + fr;                     \
    _Pragma("unroll") for (int ks = 0; ks < 2; ++ks) {                         \
      int ib = ((rowb << 6) + (ks << 5) + (kg << 3)) ^ sw;                     \
      br[(((NP) << 1) + nn) * 2 + ks] = *(const bf16x8*)&lds[(BUF) + ib]; } }  \
} while (0)

#define MFMAQ(AH, NP) do {                                                     \
  _Pragma("unroll") for (int ms = 0; ms < 4; ++ms)                             \
  _Pragma("unroll") for (int nn = 0; nn < 2; ++nn)                             \
  _Pragma("unroll") for (int ks = 0; ks < 2; ++ks)                             \
    acc[((AH) << 2) + ms][((NP) << 1) + nn] =                                  \
      __builtin_amdgcn_mfma_f32_16x16x32_bf16(ar[ms * 2 + ks],                 \
        br[(((NP) << 1) + nn) * 2 + ks],                                       \
        acc[((AH) << 2) + ms][((NP) << 1) + nn], 0, 0, 0);                     \
} while (0)

#define STAGEQ(GB, LB, QJ)                                                     \
  GLD_LDS16((GB) + (size_t)(((QJ) << 6) + srq) * GK + ssc,                     \
            &lds[(LB) + ((((QJ) << 9) + (wv << 6)) << 3)])

#define PH_MID do { __builtin_amdgcn_s_barrier();                              \
  asm volatile("s_waitcnt lgkmcnt(0)" ::: "memory");                           \
  __builtin_amdgcn_sched_barrier(0);                                           \
  __builtin_amdgcn_s_setprio(1); } while (0)

#define PH_END do { __builtin_amdgcn_s_setprio(0);                             \
  __builtin_amdgcn_s_barrier(); } while (0)

#define PH_END_V(N) do { __builtin_amdgcn_s_setprio(0);                        \
  asm volatile("s_waitcnt vmcnt(" #N ")" ::: "memory");                        \
  __builtin_amdgcn_sched_barrier(0);                                           \
  __builtin_amdgcn_s_barrier(); } while (0)

__global__ __launch_bounds__(512, 2) void gemm8(
    const unsigned short* __restrict__ A,   // GM x GK bf16
    const unsigned short* __restrict__ Bm,  // DD x GK bf16 (W row-major)
    const float* __restrict__ bias,         // DD fp32
    float* __restrict__ out) {
  __shared__ unsigned short lds[65536];     // 128 KiB

  // bijective XCD swizzle: 1024 wgs, 8 XCDs -> 128 contiguous per XCD
  int g = blockIdx.x;
  int t = ((g & 7) << 7) + (g >> 3);
  int mt = t >> 2, nt = t & 3;              // 256 M-tiles x 4 N-tiles
  int m0 = mt << 8, n0 = nt << 8;

  int tid = threadIdx.x, lane = tid & 63, wv = tid >> 6;
  int wm = wv >> 2, wn = wv & 3;            // 2M x 4N waves, each owns 128x64
  int fr = lane & 15, kg = lane >> 4;
  int sw = (fr & 7) << 3;                   // read-side swizzle (short idx)

  int srq = (wv << 3) + (lane >> 3);        // staging row within quarter
  int ssc = (((lane & 7) ^ ((lane >> 3) & 7)) << 3);  // pre-swizzled src col

  const unsigned short* Ag = A + (size_t)m0 * GK;
  const unsigned short* Bg = Bm + (size_t)n0 * GK;

  f32x4 acc[8][4] = {};
  bf16x8 ar[8], br[8];

  // ---- prologue: tile0 (8q) + tile1 {Aq0,Aq2,Bq0-3}; force tile0 ----
  {
    const unsigned short* b0 = Bg;
    const unsigned short* a1 = Ag + 64;
    const unsigned short* b1 = Bg + 64;
    STAGEQ(Ag, 0, 0); STAGEQ(Ag, 0, 1); STAGEQ(Ag, 0, 2); STAGEQ(Ag, 0, 3);
    STAGEQ(b0, 16384, 0); STAGEQ(b0, 16384, 1);
    STAGEQ(b0, 16384, 2); STAGEQ(b0, 16384, 3);
    STAGEQ(a1, 32768, 0); STAGEQ(a1, 32768, 2);
    STAGEQ(b1, 49152, 0); STAGEQ(b1, 49152, 1);
    STAGEQ(b1, 49152, 2); STAGEQ(b1, 49152, 3);
    asm volatile("s_waitcnt vmcnt(6)" ::: "memory");
    __builtin_amdgcn_sched_barrier(0);
    __builtin_amdgcn_s_barrier();
  }

  for (int i = 0; i < 7; ++i) {
    const unsigned short* a1 = Ag + (size_t)(2 * i + 1) * 64;
    const unsigned short* a2 = Ag + (size_t)(2 * i + 2) * 64;
    const unsigned short* b2 = Bg + (size_t)(2 * i + 2) * 64;
    const unsigned short* a3 = Ag + (size_t)(2 * i + 3) * 64;
    const unsigned short* b3 = Bg + (size_t)(2 * i + 3) * 64;
    // ph1: Q0 of tile 2i (buf0)
    LDA8(0, 0); LDB4(0, 16384);
    STAGEQ(a1, 32768, 1); STAGEQ(a1, 32768, 3);
    PH_MID; MFMAQ(0, 0); PH_END;
    // ph2: Q1
    LDB4(1, 16384);
    STAGEQ(a2, 0, 0); STAGEQ(a2, 0, 2);
    PH_MID; MFMAQ(0, 1); PH_END;
    // ph3: Q2
    LDA8(1, 0);
    STAGEQ(b2, 16384, 0); STAGEQ(b2, 16384, 1);
    PH_MID; MFMAQ(1, 0); PH_END;
    // ph4: Q3 (+vmcnt: forces tile 2i+1 complete)
    STAGEQ(b2, 16384, 2); STAGEQ(b2, 16384, 3);
    PH_MID; MFMAQ(1, 1); PH_END_V(6);
    // ph5: Q0 of tile 2i+1 (buf1)
    LDA8(0, 32768); LDB4(0, 49152);
    STAGEQ(a2, 0, 1); STAGEQ(a2, 0, 3);
    PH_MID; MFMAQ(0, 0); PH_END;
    // ph6: Q1
    LDB4(1, 49152);
    STAGEQ(a3, 32768, 0); STAGEQ(a3, 32768, 2);
    PH_MID; MFMAQ(0, 1); PH_END;
    // ph7: Q2
    LDA8(1, 32768);
    STAGEQ(b3, 49152, 0); STAGEQ(b3, 49152, 1);
    PH_MID; MFMAQ(1, 0); PH_END;
    // ph8: Q3 (+vmcnt: forces tile 2i+2 complete)
    STAGEQ(b3, 49152, 2); STAGEQ(b3, 49152, 3);
    PH_MID; MFMAQ(1, 1); PH_END_V(6);
  }

  // ---- peeled final iteration: tiles 14 (buf0), 15 (buf1) ----
  {
    const unsigned short* a15 = Ag + (size_t)15 * 64;
    LDA8(0, 0); LDB4(0, 16384);
    STAGEQ(a15, 32768, 1); STAGEQ(a15, 32768, 3);
    PH_MID; MFMAQ(0, 0); PH_END;
    LDB4(1, 16384); PH_MID; MFMAQ(0, 1); PH_END;
    LDA8(1, 0);     PH_MID; MFMAQ(1, 0); PH_END;
    PH_MID; MFMAQ(1, 1); PH_END_V(0);
    LDA8(0, 32768); LDB4(0, 49152); PH_MID; MFMAQ(0, 0); PH_END;
    LDB4(1, 49152); PH_MID; MFMAQ(0, 1); PH_END;
    LDA8(1, 32768); PH_MID; MFMAQ(1, 0); PH_END;
    PH_MID; MFMAQ(1, 1);
    __builtin_amdgcn_s_setprio(0);
  }

  // ---- epilogue: C/D layout col=lane&15, row=(lane>>4)*4+j ----
  int r0 = kg << 2, cc = fr;
#pragma unroll
  for (int ni = 0; ni < 4; ++ni) {
    int gcol = n0 + (wn << 6) + (ni << 4) + cc;
    float bv = bias[gcol];
#pragma unroll
    for (int mi = 0; mi < 8; ++mi) {
      int gr = m0 + (wm << 7) + (mi << 4) + r0;
#pragma unroll
      for (int j = 0; j < 4; ++j) {
        int grow = gr + j;                       // m index = b*4096 + s
        size_t o = ((size_t)(grow + (grow >> 12)) << 10) + gcol;
        out[o] = acc[mi][ni][j] + bv;
      }
    }
  }
}

// ---------------- combine partials -> cos -> per-block argmax ---------------
__global__ __launch_bounds__(256) void cos_combine(
    const float* __restrict__ pd, const float* __restrict__ pn,
    float* __restrict__ pscore, int* __restrict__ pidx) {
  __shared__ float rs[4][16];
  __shared__ int ri[4][16];
  int tid = threadIdx.x, lane = tid & 63, w = tid >> 6;
  int k = blockIdx.x * 256 + tid;

  float d[16] = {0.f, 0.f, 0.f, 0.f, 0.f, 0.f, 0.f, 0.f,
                 0.f, 0.f, 0.f, 0.f, 0.f, 0.f, 0.f, 0.f};
  float nrm = 0.f;
#pragma unroll
  for (int dc = 0; dc < 4; ++dc) {
    const float4* p = (const float4*)(pd + ((size_t)dc * KK + k) * 16);
#pragma unroll
    for (int i = 0; i < 4; ++i) {
      float4 v = p[i];
      d[i * 4 + 0] += v.x; d[i * 4 + 1] += v.y;
      d[i * 4 + 2] += v.z; d[i * 4 + 3] += v.w;
    }
    nrm += pn[(size_t)dc * KK + k];
  }
  float inv = rsqrtf(fmaxf(nrm, 1e-24f));

#pragma unroll
  for (int b = 0; b < 16; ++b) {
    float s = d[b] * inv;
    int i = k;
#pragma unroll
    for (int off = 32; off; off >>= 1) {
      float s2 = __shfl_xor(s, off);
      int i2 = __shfl_xor(i, off);
      if (s2 > s || (s2 == s && i2 < i)) { s = s2; i = i2; }
    }
    if (lane == 0) { rs[w][b] = s; ri[w][b] = i; }
  }
  __syncthreads();
  if (tid < 16) {
    float bs = rs[0][tid]; int bi = ri[0][tid];
#pragma unroll
    for (int w2 = 1; w2 < 4; ++w2) {
      float s = rs[w2][tid]; int i = ri[w2][tid];
      if (s > bs || (s == bs && i < bi)) { bs = s; bi = i; }
    }
    pscore[(size_t)tid * gridDim.x + blockIdx.x] = bs;
    pidx[(size_t)tid * gridDim.x + blockIdx.x] = bi;
  }
}

// ---------------- final argmax reduce + token gather + l2norm ---------------
__global__ __launch_bounds__(256) void select_write(
    const float* __restrict__ pscore, const int* __restrict__ pidx, int nb,
    const int* __restrict__ ktv, const float* __restrict__ values,
    float* __restrict__ out) {
  __shared__ float ss[4];
  __shared__ int si[4];
  __shared__ float snrm;
  __shared__ int swin;
  int b = blockIdx.x, tid = threadIdx.x, lane = tid & 63, wv = tid >> 6;

  float best = -1e30f;
  int bidx = 0x7fffffff;
  for (int t = tid; t < nb; t += 256) {
    float s = pscore[(size_t)b * nb + t];
    int i = pidx[(size_t)b * nb + t];
    if (s > best || (s == best && i < bidx)) { best = s; bidx = i; }
  }
#pragma unroll
  for (int off = 32; off; off >>= 1) {
    float s = __shfl_xor(best, off);
    int i = __shfl_xor(bidx, off);
    if (s > best || (s == best && i < bidx)) { best = s; bidx = i; }
  }
  if (lane == 0) { ss[wv] = best; si[wv] = bidx; }
  __syncthreads();
  if (tid == 0) {
    float bs = ss[0]; int bi = si[0];
    for (int w2 = 1; w2 < 4; ++w2)
      if (ss[w2] > bs || (ss[w2] == bs && si[w2] < bi)) { bs = ss[w2]; bi = si[w2]; }
    swin = ktv[bi];   // key_to_value mapping
  }
  __syncthreads();
  int idx = swin;

  float4 v = ((const float4*)(values + (size_t)idx * DD))[tid];
  float nrm = v.x * v.x + v.y * v.y + v.z * v.z + v.w * v.w;
#pragma unroll
  for (int off = 32; off; off >>= 1) nrm += __shfl_xor(nrm, off);
  if (lane == 0) ss[wv] = nrm;
  __syncthreads();
  if (tid == 0) snrm = rsqrtf(fmaxf(ss[0] + ss[1] + ss[2] + ss[3], 1e-24f));
  __syncthreads();
  float inv = snrm;

  float4 o;
  o.x = v.x * inv; o.y = v.y * inv; o.z = v.z * inv; o.w = v.w * inv;
  ((float4*)(out + (((size_t)b * (SS + 1) + SS) << 10)))[tid] = o;
}

// ---------------- launcher ---------------------------------------------------
extern "C" void kernel_launch(void* const* d_in, const int* in_sizes, int n_in,
                              void* d_out, int out_size, void* d_ws,
                              size_t ws_size, hipStream_t stream) {
  const float* hidden = (const float*)d_in[0];
  const float* csig   = (const float*)d_in[1];
  const float* keys   = (const float*)d_in[2];
  const float* values = (const float*)d_in[3];
  const int*   ktv    = (const int*)d_in[4];
  const float* W      = (const float*)d_in[5];
  const float* bias   = (const float*)d_in[6];
  float* out = (float*)d_out;

  char* ws = (char*)d_ws;
  const size_t HB = (size_t)GM * GK * 2;    // 128 MB  bf16 hidden
  const size_t WB = (size_t)DD * GK * 2;    // 2 MB    bf16 W
  const size_t PDB = (size_t)4 * KK * 16 * 4;  // 16 MB  partial dots
  const size_t PNB = (size_t)4 * KK * 4;       // 1 MB   partial norms
  const size_t PSB = (size_t)16 * 256 * 4;     // 16 KB

  unsigned short* hbf = (unsigned short*)ws;
  unsigned short* wbf = (unsigned short*)(ws + HB);

  if (ws_size >= HB + WB + PDB + PNB + 2 * PSB) {
    // parallel layout: pd/pn disjoint from hbf -> single fused prep launch
    float* pd     = (float*)(ws + HB + WB);
    float* pn     = (float*)(ws + HB + WB + PDB);
    float* pscore = (float*)(ws + HB + WB + PDB + PNB);
    int*   pidx   = (int*)(ws + HB + WB + PDB + PNB + PSB);

    prep_fused<<<5632, 256, 0, stream>>>(keys, csig, pd, pn,
                                         hidden, hbf, W, wbf);
    cos_combine<<<256, 256, 0, stream>>>(pd, pn, pscore, pidx);
    gemm8<<<1024, 512, 0, stream>>>(hbf, wbf, bias, out);
    select_write<<<BB, 256, 0, stream>>>(pscore, pidx, 256, ktv, values, out);
  } else {
    // serial layout: pd/pn alias the hbf region (cos finishes before cvt)
    float* pd     = (float*)ws;
    float* pn     = (float*)(ws + PDB);
    float* pscore = (float*)(ws + HB + WB);
    int*   pidx   = (int*)(ws + HB + WB + PSB);

    cos_part4_k<<<1024, 256, 0, stream>>>(keys, csig, pd, pn);
    cos_combine<<<256, 256, 0, stream>>>(pd, pn, pscore, pidx);
    cvt_bf16<<<4096, 256, 0, stream>>>(hidden, hbf, GM * GK / 8);
    cvt_bf16<<<512, 256, 0, stream>>>(W, wbf, DD * GK / 8);
    gemm8<<<1024, 512, 0, stream>>>(hbf, wbf, bias, out);
    select_write<<<BB, 256, 0, stream>>>(pscore, pidx, 256, ktv, values, out);
  }
}

// Round 7
// 379.929 us; speedup vs baseline: 1.5093x; 1.0846x over previous
//
#include <hip/hip_runtime.h>

// Problem constants (fixed by setup_inputs)
constexpr int BB = 16;         // batch
constexpr int SS = 4096;       // seq
constexpr int DD = 1024;       // hidden dim
constexpr int KK = 65536;      // num keys
constexpr int GM = BB * SS;    // GEMM M = 65536
constexpr int GK = DD;         // GEMM K = 1024

typedef __attribute__((ext_vector_type(8))) short bf16x8;
typedef __attribute__((ext_vector_type(4))) float f32x4;
typedef __attribute__((ext_vector_type(8))) unsigned short ushort8;

#define GLD_LDS16(g, l)                                                        \
  __builtin_amdgcn_global_load_lds(                                            \
      (const __attribute__((address_space(1))) void*)(g),                      \
      (__attribute__((address_space(3))) void*)(l), 16, 0, 0)

__device__ __forceinline__ unsigned short f2bf(float x) {
  unsigned u = __float_as_uint(x);
  u += 0x7fffu + ((u >> 16) & 1u);   // RNE
  return (unsigned short)(u >> 16);
}

// ---------------- fp32 -> bf16 conversion (grid-stride, 8/thread/iter) ------
__device__ __forceinline__ void cvt_body(const float* __restrict__ in,
                                         unsigned short* __restrict__ out,
                                         int i) {
  const float4* p = (const float4*)in + (size_t)i * 2;
  float4 a = p[0], b = p[1];
  ushort8 r;
  r[0] = f2bf(a.x); r[1] = f2bf(a.y); r[2] = f2bf(a.z); r[3] = f2bf(a.w);
  r[4] = f2bf(b.x); r[5] = f2bf(b.y); r[6] = f2bf(b.z); r[7] = f2bf(b.w);
  *(ushort8*)(out + (size_t)i * 8) = r;
}

__global__ void cvt_bf16(const float* __restrict__ in,
                         unsigned short* __restrict__ out, int n8) {
  int stride = gridDim.x * blockDim.x;
  for (int i = blockIdx.x * blockDim.x + threadIdx.x; i < n8; i += stride)
    cvt_body(in, out, i);
}

// ---------------- q split: csig -> bf16 hi + bf16 lo residual ---------------
__global__ __launch_bounds__(256) void qsplit(const float* __restrict__ csig,
                                              unsigned short* __restrict__ qh,
                                              unsigned short* __restrict__ ql) {
  int i = blockIdx.x * 256 + threadIdx.x;   // 64 blocks cover 16384
  float v = csig[i];
  unsigned short h = f2bf(v);
  float hf = __uint_as_float((unsigned)h << 16);
  qh[i] = h;
  ql[i] = f2bf(v - hf);
}

// ---------------- cos scores via split-bf16 MFMA ----------------------------
// Block = 256 thr = 4 waves; wave handles 16 keys (cols), all 16 batches.
// Lane (fr=lane&15, kg=lane>>4): key = base + fr; reads 32B of its key row at
// d = t*32 + kg*8 (wave consumes 16 full 128B lines -> 100% utilization).
// Keys split in-register to bf16 hi/lo; dot = qh*kh + ql*kh + qh*kl (3 MFMA,
// error ~2^-18 << top-2 gap ~0.0076).  Norm exact fp32.  No LDS staging.
__global__ __launch_bounds__(256) void cos_mfma(
    const float* __restrict__ keys,          // KK x DD fp32
    const unsigned short* __restrict__ qh,   // 16 x DD bf16 hi
    const unsigned short* __restrict__ ql,   // 16 x DD bf16 lo
    float* __restrict__ pscore,              // [16][1024]
    int* __restrict__ pidx) {
  __shared__ float rs[4][16];
  __shared__ int ri[4][16];
  int tid = threadIdx.x, lane = tid & 63, w = tid >> 6;
  int fr = lane & 15, kg = lane >> 4;
  int key = blockIdx.x * 64 + w * 16 + fr;

  const float* krow = keys + (size_t)key * DD + kg * 8;
  const unsigned short* qhp = qh + fr * DD + kg * 8;
  const unsigned short* qlp = ql + fr * DD + kg * 8;

  f32x4 acc = {};
  float nrm = 0.f;

  float4 ka = *(const float4*)krow;
  float4 kb = *(const float4*)(krow + 4);
  bf16x8 h8 = *(const bf16x8*)qhp;
  bf16x8 l8 = *(const bf16x8*)qlp;

  for (int t = 0; t < 32; ++t) {
    float4 kc = ka, kd = kb;
    bf16x8 hh = h8, ll = l8;
    if (t + 1 < 32) {   // prefetch next chunk (T14)
      ka = *(const float4*)(krow + (t + 1) * 32);
      kb = *(const float4*)(krow + (t + 1) * 32 + 4);
      h8 = *(const bf16x8*)(qhp + (t + 1) * 32);
      l8 = *(const bf16x8*)(qlp + (t + 1) * 32);
    }
    float ke[8] = {kc.x, kc.y, kc.z, kc.w, kd.x, kd.y, kd.z, kd.w};
    ushort8 khv, klv;
#pragma unroll
    for (int j = 0; j < 8; ++j) {
      float v = ke[j];
      unsigned short h = f2bf(v);
      float hf = __uint_as_float((unsigned)h << 16);
      khv[j] = h;
      klv[j] = f2bf(v - hf);
      nrm = fmaf(v, v, nrm);
    }
    bf16x8 kh8 = *(bf16x8*)&khv, kl8 = *(bf16x8*)&klv;
    acc = __builtin_amdgcn_mfma_f32_16x16x32_bf16(hh, kh8, acc, 0, 0, 0);
    acc = __builtin_amdgcn_mfma_f32_16x16x32_bf16(ll, kh8, acc, 0, 0, 0);
    acc = __builtin_amdgcn_mfma_f32_16x16x32_bf16(hh, kl8, acc, 0, 0, 0);
  }

  // full ||k||^2: reduce across the 4 kg-lanes of this key
  nrm += __shfl_xor(nrm, 16);
  nrm += __shfl_xor(nrm, 32);
  float inv = rsqrtf(fmaxf(nrm, 1e-24f));

  // lane holds batches kg*4+j for its key; argmax over fr within wave
#pragma unroll
  for (int j = 0; j < 4; ++j) {
    float s = acc[j] * inv;
    int i = key;
#pragma unroll
    for (int off = 1; off < 16; off <<= 1) {
      float s2 = __shfl_xor(s, off);
      int i2 = __shfl_xor(i, off);
      if (s2 > s || (s2 == s && i2 < i)) { s = s2; i = i2; }
    }
    if (fr == 0) { rs[w][kg * 4 + j] = s; ri[w][kg * 4 + j] = i; }
  }
  __syncthreads();
  if (tid < 16) {
    float bs = rs[0][tid]; int bi = ri[0][tid];
#pragma unroll
    for (int w2 = 1; w2 < 4; ++w2) {
      float s = rs[w2][tid]; int i = ri[w2][tid];
      if (s > bs || (s == bs && i < bi)) { bs = s; bi = i; }
    }
    pscore[(size_t)tid * gridDim.x + blockIdx.x] = bs;
    pidx[(size_t)tid * gridDim.x + blockIdx.x] = bi;
  }
}

// =====================  GEMM: 256x256 tile, 8-phase (R3-proven) =============
// C[m,n] = sum_k A[m,k]*W[n,k] + bias[n].  BM=BN=256, BK=64, 8 waves (2Mx4N),
// LDS 128 KiB (2 buf x (A 32KB + B 32KB)).  K = 1024 -> 16 K-tiles, 8 iters.
// vmcnt(6) at ph4/ph8 forces next tile fully landed before its first read.
// LDS swizzle: short_idx ^= (row&7)<<3, applied as inverse-permuted GLOBAL
// source + swizzled ds_read (both-sides rule).

#define LDA8(AH, BUF) do {                                                     \
  _Pragma("unroll") for (int ms = 0; ms < 4; ++ms) {                           \
    int rowa = (wm << 7) + ((AH) << 6) + (ms << 4) + fr;                       \
    _Pragma("unroll") for (int ks = 0; ks < 2; ++ks) {                         \
      int ia = ((rowa << 6) + (ks << 5) + (kg << 3)) ^ sw;                     \
      ar[ms * 2 + ks] = *(const bf16x8*)&lds[(BUF) + ia]; } }                  \
} while (0)

#define LDB4(NP, BUF) do {                                                     \
  _Pragma("unroll") for (int nn = 0; nn < 2; ++nn) {                           \
    int rowb = (wn << 6) + ((((NP) << 1) + nn) << 4) + fr;                     \
    _Pragma("unroll") for (int ks = 0; ks < 2; ++ks) {                         \
      int ib = ((rowb << 6) + (ks << 5) + (kg << 3)) ^ sw;                     \
      br[(((NP) << 1) + nn) * 2 + ks] = *(const bf16x8*)&lds[(BUF) + ib]; } }  \
} while (0)

#define MFMAQ(AH, NP) do {                                                     \
  _Pragma("unroll") for (int ms = 0; ms < 4; ++ms)                             \
  _Pragma("unroll") for (int nn = 0; nn < 2; ++nn)                             \
  _Pragma("unroll") for (int ks = 0; ks < 2; ++ks)                             \
    acc[((AH) << 2) + ms][((NP) << 1) + nn] =                                  \
      __builtin_amdgcn_mfma_f32_16x16x32_bf16(ar[ms * 2 + ks],                 \
        br[(((NP) << 1) + nn) * 2 + ks],                                       \
        acc[((AH) << 2) + ms][((NP) << 1) + nn], 0, 0, 0);                     \
} while (0)

#define STAGEQ(GB, LB, QJ)                                                     \
  GLD_LDS16((GB) + (size_t)(((QJ) << 6) + srq) * GK + ssc,                     \
            &lds[(LB) + ((((QJ) << 9) + (wv << 6)) << 3)])

#define PH_MID do { __builtin_amdgcn_s_barrier();                              \
  asm volatile("s_waitcnt lgkmcnt(0)" ::: "memory");                           \
  __builtin_amdgcn_sched_barrier(0);                                           \
  __builtin_amdgcn_s_setprio(1); } while (0)

#define PH_END do { __builtin_amdgcn_s_setprio(0);                             \
  __builtin_amdgcn_s_barrier(); } while (0)

#define PH_END_V(N) do { __builtin_amdgcn_s_setprio(0);                        \
  asm volatile("s_waitcnt vmcnt(" #N ")" ::: "memory");                        \
  __builtin_amdgcn_sched_barrier(0);                                           \
  __builtin_amdgcn_s_barrier(); } while (0)

__global__ __launch_bounds__(512, 2) void gemm8(
    const unsigned short* __restrict__ A,   // GM x GK bf16
    const unsigned short* __restrict__ Bm,  // DD x GK bf16 (W row-major)
    const float* __restrict__ bias,         // DD fp32
    float* __restrict__ out) {
  __shared__ unsigned short lds[65536];     // 128 KiB

  // bijective XCD swizzle: 1024 wgs, 8 XCDs -> 128 contiguous per XCD
  int g = blockIdx.x;
  int t = ((g & 7) << 7) + (g >> 3);
  int mt = t >> 2, nt = t & 3;              // 256 M-tiles x 4 N-tiles
  int m0 = mt << 8, n0 = nt << 8;

  int tid = threadIdx.x, lane = tid & 63, wv = tid >> 6;
  int wm = wv >> 2, wn = wv & 3;            // 2M x 4N waves, each owns 128x64
  int fr = lane & 15, kg = lane >> 4;
  int sw = (fr & 7) << 3;                   // read-side swizzle (short idx)

  int srq = (wv << 3) + (lane >> 3);        // staging row within quarter
  int ssc = (((lane & 7) ^ ((lane >> 3) & 7)) << 3);  // pre-swizzled src col

  const unsigned short* Ag = A + (size_t)m0 * GK;
  const unsigned short* Bg = Bm + (size_t)n0 * GK;

  f32x4 acc[8][4] = {};
  bf16x8 ar[8], br[8];

  // ---- prologue: tile0 (8q) + tile1 {Aq0,Aq2,Bq0-3}; force tile0 ----
  {
    const unsigned short* b0 = Bg;
    const unsigned short* a1 = Ag + 64;
    const unsigned short* b1 = Bg + 64;
    STAGEQ(Ag, 0, 0); STAGEQ(Ag, 0, 1); STAGEQ(Ag, 0, 2); STAGEQ(Ag, 0, 3);
    STAGEQ(b0, 16384, 0); STAGEQ(b0, 16384, 1);
    STAGEQ(b0, 16384, 2); STAGEQ(b0, 16384, 3);
    STAGEQ(a1, 32768, 0); STAGEQ(a1, 32768, 2);
    STAGEQ(b1, 49152, 0); STAGEQ(b1, 49152, 1);
    STAGEQ(b1, 49152, 2); STAGEQ(b1, 49152, 3);
    asm volatile("s_waitcnt vmcnt(6)" ::: "memory");
    __builtin_amdgcn_sched_barrier(0);
    __builtin_amdgcn_s_barrier();
  }

  for (int i = 0; i < 7; ++i) {
    const unsigned short* a1 = Ag + (size_t)(2 * i + 1) * 64;
    const unsigned short* a2 = Ag + (size_t)(2 * i + 2) * 64;
    const unsigned short* b2 = Bg + (size_t)(2 * i + 2) * 64;
    const unsigned short* a3 = Ag + (size_t)(2 * i + 3) * 64;
    const unsigned short* b3 = Bg + (size_t)(2 * i + 3) * 64;
    // ph1: Q0 of tile 2i (buf0)
    LDA8(0, 0); LDB4(0, 16384);
    STAGEQ(a1, 32768, 1); STAGEQ(a1, 32768, 3);
    PH_MID; MFMAQ(0, 0); PH_END;
    // ph2: Q1
    LDB4(1, 16384);
    STAGEQ(a2, 0, 0); STAGEQ(a2, 0, 2);
    PH_MID; MFMAQ(0, 1); PH_END;
    // ph3: Q2
    LDA8(1, 0);
    STAGEQ(b2, 16384, 0); STAGEQ(b2, 16384, 1);
    PH_MID; MFMAQ(1, 0); PH_END;
    // ph4: Q3 (+vmcnt: forces tile 2i+1 complete)
    STAGEQ(b2, 16384, 2); STAGEQ(b2, 16384, 3);
    PH_MID; MFMAQ(1, 1); PH_END_V(6);
    // ph5: Q0 of tile 2i+1 (buf1)
    LDA8(0, 32768); LDB4(0, 49152);
    STAGEQ(a2, 0, 1); STAGEQ(a2, 0, 3);
    PH_MID; MFMAQ(0, 0); PH_END;
    // ph6: Q1
    LDB4(1, 49152);
    STAGEQ(a3, 32768, 0); STAGEQ(a3, 32768, 2);
    PH_MID; MFMAQ(0, 1); PH_END;
    // ph7: Q2
    LDA8(1, 32768);
    STAGEQ(b3, 49152, 0); STAGEQ(b3, 49152, 1);
    PH_MID; MFMAQ(1, 0); PH_END;
    // ph8: Q3 (+vmcnt: forces tile 2i+2 complete)
    STAGEQ(b3, 49152, 2); STAGEQ(b3, 49152, 3);
    PH_MID; MFMAQ(1, 1); PH_END_V(6);
  }

  // ---- peeled final iteration: tiles 14 (buf0), 15 (buf1) ----
  {
    const unsigned short* a15 = Ag + (size_t)15 * 64;
    LDA8(0, 0); LDB4(0, 16384);
    STAGEQ(a15, 32768, 1); STAGEQ(a15, 32768, 3);
    PH_MID; MFMAQ(0, 0); PH_END;
    LDB4(1, 16384); PH_MID; MFMAQ(0, 1); PH_END;
    LDA8(1, 0);     PH_MID; MFMAQ(1, 0); PH_END;
    PH_MID; MFMAQ(1, 1); PH_END_V(0);
    LDA8(0, 32768); LDB4(0, 49152); PH_MID; MFMAQ(0, 0); PH_END;
    LDB4(1, 49152); PH_MID; MFMAQ(0, 1); PH_END;
    LDA8(1, 32768); PH_MID; MFMAQ(1, 0); PH_END;
    PH_MID; MFMAQ(1, 1);
    __builtin_amdgcn_s_setprio(0);
  }

  // ---- epilogue: C/D layout col=lane&15, row=(lane>>4)*4+j ----
  int r0 = kg << 2, cc = fr;
#pragma unroll
  for (int ni = 0; ni < 4; ++ni) {
    int gcol = n0 + (wn << 6) + (ni << 4) + cc;
    float bv = bias[gcol];
#pragma unroll
    for (int mi = 0; mi < 8; ++mi) {
      int gr = m0 + (wm << 7) + (mi << 4) + r0;
#pragma unroll
      for (int j = 0; j < 4; ++j) {
        int grow = gr + j;                       // m index = b*4096 + s
        size_t o = ((size_t)(grow + (grow >> 12)) << 10) + gcol;
        out[o] = acc[mi][ni][j] + bv;
      }
    }
  }
}

// ---------------- final argmax reduce + token gather + l2norm ---------------
__global__ __launch_bounds__(256) void select_write(
    const float* __restrict__ pscore, const int* __restrict__ pidx, int nb,
    const int* __restrict__ ktv, const float* __restrict__ values,
    float* __restrict__ out) {
  __shared__ float ss[4];
  __shared__ int si[4];
  __shared__ float snrm;
  __shared__ int swin;
  int b = blockIdx.x, tid = threadIdx.x, lane = tid & 63, wv = tid >> 6;

  float best = -1e30f;
  int bidx = 0x7fffffff;
  for (int t = tid; t < nb; t += 256) {
    float s = pscore[(size_t)b * nb + t];
    int i = pidx[(size_t)b * nb + t];
    if (s > best || (s == best && i < bidx)) { best = s; bidx = i; }
  }
#pragma unroll
  for (int off = 32; off; off >>= 1) {
    float s = __shfl_xor(best, off);
    int i = __shfl_xor(bidx, off);
    if (s > best || (s == best && i < bidx)) { best = s; bidx = i; }
  }
  if (lane == 0) { ss[wv] = best; si[wv] = bidx; }
  __syncthreads();
  if (tid == 0) {
    float bs = ss[0]; int bi = si[0];
    for (int w2 = 1; w2 < 4; ++w2)
      if (ss[w2] > bs || (ss[w2] == bs && si[w2] < bi)) { bs = ss[w2]; bi = si[w2]; }
    swin = ktv[bi];   // key_to_value mapping
  }
  __syncthreads();
  int idx = swin;

  float4 v = ((const float4*)(values + (size_t)idx * DD))[tid];
  float nrm = v.x * v.x + v.y * v.y + v.z * v.z + v.w * v.w;
#pragma unroll
  for (int off = 32; off; off >>= 1) nrm += __shfl_xor(nrm, off);
  if (lane == 0) ss[wv] = nrm;
  __syncthreads();
  if (tid == 0) snrm = rsqrtf(fmaxf(ss[0] + ss[1] + ss[2] + ss[3], 1e-24f));
  __syncthreads();
  float inv = snrm;

  float4 o;
  o.x = v.x * inv; o.y = v.y * inv; o.z = v.z * inv; o.w = v.w * inv;
  ((float4*)(out + (((size_t)b * (SS + 1) + SS) << 10)))[tid] = o;
}

// ---------------- launcher ---------------------------------------------------
extern "C" void kernel_launch(void* const* d_in, const int* in_sizes, int n_in,
                              void* d_out, int out_size, void* d_ws,
                              size_t ws_size, hipStream_t stream) {
  const float* hidden = (const float*)d_in[0];
  const float* csig   = (const float*)d_in[1];
  const float* keys   = (const float*)d_in[2];
  const float* values = (const float*)d_in[3];
  const int*   ktv    = (const int*)d_in[4];
  const float* W      = (const float*)d_in[5];
  const float* bias   = (const float*)d_in[6];
  float* out = (float*)d_out;

  char* ws = (char*)d_ws;
  const size_t HB = (size_t)GM * GK * 2;        // 128 MB  bf16 hidden
  const size_t WB = (size_t)DD * GK * 2;        // 2 MB    bf16 W
  const size_t QB = (size_t)BB * DD * 2;        // 32 KB   qh / ql each
  const size_t PSB = (size_t)BB * 1024 * 4;     // 64 KB   pscore / pidx each

  unsigned short* hbf = (unsigned short*)ws;
  unsigned short* wbf = (unsigned short*)(ws + HB);
  unsigned short* qh  = (unsigned short*)(ws + HB + WB);
  unsigned short* ql  = (unsigned short*)(ws + HB + WB + QB);
  float* pscore = (float*)(ws + HB + WB + 2 * QB);
  int*   pidx   = (int*)(ws + HB + WB + 2 * QB + PSB);

  // 1) q hi/lo split (tiny)
  qsplit<<<64, 256, 0, stream>>>(csig, qh, ql);

  // 2) cos scores + per-block argmax (split-bf16 MFMA, no LDS)
  cos_mfma<<<1024, 256, 0, stream>>>(keys, qh, ql, pscore, pidx);

  // 3) conversions
  cvt_bf16<<<4096, 256, 0, stream>>>(hidden, hbf, GM * GK / 8);
  cvt_bf16<<<512, 256, 0, stream>>>(W, wbf, DD * GK / 8);

  // 4) GEMM + bias into out rows s<4096 (256^2 8-phase)
  gemm8<<<1024, 512, 0, stream>>>(hbf, wbf, bias, out);

  // 5) final reduce + token row s=4096
  select_write<<<BB, 256, 0, stream>>>(pscore, pidx, 1024, ktv, values, out);
}